// Round 10
// baseline (991.971 us; speedup 1.0000x reference)
//
#include <hip/hip_runtime.h>
#include <hip/hip_fp16.h>
#include <math.h>

#define B_ 128
#define T_ 256
#define E_ 300
#define H_ 256
#define N5_ 1280
#define NSTEPS 511
#define DMAX 8
#define PFD 4

typedef _Float16 half8_t __attribute__((ext_vector_type(8)));
typedef float float4_t __attribute__((ext_vector_type(4)));
typedef int i4v __attribute__((ext_vector_type(4)));
typedef unsigned int u4v __attribute__((ext_vector_type(4)));

__device__ __forceinline__ float sigm(float x){ return 1.f/(1.f + expf(-x)); }

// ---------------------------------------------------------------------------
// K0a: per-column absmax scale for hl-part of Wr (rows 0..255).
// ---------------------------------------------------------------------------
__global__ __launch_bounds__(64) void k0a_scale(const float* __restrict__ Wr,
    float* __restrict__ scales){
  const int n = blockIdx.x, t = threadIdx.x;
  float m = 0.f;
  #pragma unroll
  for (int j=0;j<4;j++) m = fmaxf(m, fabsf(Wr[(size_t)(t+64*j)*N5_ + n]));
  #pragma unroll
  for (int off=32; off; off>>=1) m = fmaxf(m, __shfl_xor(m, off, 64));
  if (t==0) scales[n] = fmaxf(m, 1e-20f) * (1.f/127.f);
}

// ---------------------------------------------------------------------------
// K0b: quantize hl-part of Wr (rows 0..255) into int8 MFMA B-fragments.
// Frag f = w*80 + g*16 + cg*4 + kc ; lane l holds col = g*256+w*64+cg*16+(l&15),
// dword r byte j -> k = kc*64 + (l>>4)*16 + r*4 + j.
// ---------------------------------------------------------------------------
__global__ __launch_bounds__(256) void k0b_quant(const float* __restrict__ Wr,
    const float* __restrict__ scales, uint4* __restrict__ W4){
  int idx = blockIdx.x*256 + threadIdx.x;
  if (idx >= 20480) return;
  const int f    = idx >> 6;
  const int lane = idx & 63;
  const int w    = f / 80;
  const int r80  = f - w*80;
  const int g    = r80 >> 4;
  const int cg   = (r80 >> 2) & 3;
  const int kc   = r80 & 3;
  const int ml   = lane & 15, quad = lane >> 4;
  const int col  = g*256 + w*64 + cg*16 + ml;
  const float inv = 1.f / scales[col];
  unsigned int d[4];
  #pragma unroll
  for (int r=0; r<4; r++){
    unsigned int acc = 0;
    #pragma unroll
    for (int j=0; j<4; j++){
      const int k = kc*64 + quad*16 + r*4 + j;
      float wv = Wr[(size_t)k*N5_ + col];
      int q = (int)rintf(wv * inv);
      q = q > 127 ? 127 : (q < -127 ? -127 : q);
      acc |= ((unsigned int)(q & 255)) << (8*j);
    }
    d[r] = acc;
  }
  uint4 v; v.x=d[0]; v.y=d[1]; v.z=d[2]; v.w=d[3];
  W4[idx] = v;
}

// ---------------------------------------------------------------------------
// K1: fused projection GEMM (unchanged).
// ---------------------------------------------------------------------------
__global__ __launch_bounds__(256) void k1_proj(
    const float* __restrict__ x, const float* __restrict__ Wp, const float* __restrict__ bp,
    const float* __restrict__ Wg, const float* __restrict__ bg,
    _Float16* __restrict__ h2, _Float16* __restrict__ c2){
  __shared__ __align__(16) _Float16 As [64*32];
  __shared__ __align__(16) _Float16 BsP[64*32];
  __shared__ __align__(16) _Float16 BsG[64*32];
  const int tid = threadIdx.x;
  const int row0 = blockIdx.x * 64;
  const int n0   = blockIdx.y * 64;
  const int wave = tid >> 6, lane = tid & 63;
  const int ml = lane & 15, quad = lane >> 4;
  float4_t accP[4], accG[4];
  #pragma unroll
  for (int i=0;i<4;i++){ accP[i]=(float4_t)(0.f); accG[i]=(float4_t)(0.f); }
  const int ar = tid >> 2, ak = (tid & 3) * 8;
  const int bk = tid >> 3, bn = (tid & 7) * 8;
  for (int kk = 0; kk < E_; kk += 32){
    __syncthreads();
    {
      const float* src = x + (size_t)(row0 + ar)*E_ + kk + ak;
      float v[8];
      #pragma unroll
      for (int q=0;q<2;q++){
        if (kk + ak + q*4 + 4 <= E_){
          float4_t f = *(const float4_t*)(src + q*4);
          v[q*4+0]=f.x; v[q*4+1]=f.y; v[q*4+2]=f.z; v[q*4+3]=f.w;
        } else {
          #pragma unroll
          for (int j=0;j<4;j++){ int kg = kk+ak+q*4+j; v[q*4+j] = (kg<E_) ? src[q*4+j] : 0.f; }
        }
      }
      #pragma unroll
      for (int j=0;j<8;j++) As[ar*32 + ak + j] = (_Float16)v[j];
    }
    {
      const int kg = kk + bk;
      if (kg < E_){
        const float* sp_ = Wp + (size_t)kg*H_ + n0 + bn;
        const float* sg_ = Wg + (size_t)kg*H_ + n0 + bn;
        float4_t p0 = *(const float4_t*)sp_, p1 = *(const float4_t*)(sp_+4);
        float4_t g0 = *(const float4_t*)sg_, g1 = *(const float4_t*)(sg_+4);
        float pv[8]={p0.x,p0.y,p0.z,p0.w,p1.x,p1.y,p1.z,p1.w};
        float gv[8]={g0.x,g0.y,g0.z,g0.w,g1.x,g1.y,g1.z,g1.w};
        #pragma unroll
        for (int j=0;j<8;j++){ BsP[(bn+j)*32+bk]=(_Float16)pv[j]; BsG[(bn+j)*32+bk]=(_Float16)gv[j]; }
      } else {
        #pragma unroll
        for (int j=0;j<8;j++){ BsP[(bn+j)*32+bk]=(_Float16)0.f; BsG[(bn+j)*32+bk]=(_Float16)0.f; }
      }
    }
    __syncthreads();
    half8_t a = *(const half8_t*)&As[(wave*16 + ml)*32 + quad*8];
    #pragma unroll
    for (int nt=0; nt<4; nt++){
      half8_t b1 = *(const half8_t*)&BsP[(nt*16 + ml)*32 + quad*8];
      accP[nt] = __builtin_amdgcn_mfma_f32_16x16x32_f16(a, b1, accP[nt], 0,0,0);
      half8_t b2 = *(const half8_t*)&BsG[(nt*16 + ml)*32 + quad*8];
      accG[nt] = __builtin_amdgcn_mfma_f32_16x16x32_f16(a, b2, accG[nt], 0,0,0);
    }
  }
  #pragma unroll
  for (int nt=0; nt<4; nt++){
    #pragma unroll
    for (int r=0;r<4;r++){
      int row = row0 + wave*16 + quad*4 + r;
      int col = n0 + nt*16 + ml;
      float c = accP[nt][r] + bp[col];
      float g = accG[nt][r] + bg[col];
      float h = sigm(g) * tanhf(c);
      size_t o = (size_t)row*H_ + col;
      c2[o] = (_Float16)c;
      h2[o] = (_Float16)h;
    }
  }
}

// ---------------------------------------------------------------------------
// K2: R = h_buf @ Wr[256:512,:] + br -> f16 R2 (unchanged)
// ---------------------------------------------------------------------------
__global__ __launch_bounds__(256) void k2_rproj(
    const _Float16* __restrict__ h2, const float* __restrict__ Wr, const float* __restrict__ br,
    _Float16* __restrict__ R2){
  __shared__ __align__(16) _Float16 As[64*32];
  __shared__ __align__(16) _Float16 Bs[64*32];
  const int tid = threadIdx.x;
  const int row0 = blockIdx.x*64, n0 = blockIdx.y*64;
  const int wave = tid>>6, lane = tid&63, ml = lane&15, quad = lane>>4;
  float4_t acc[4];
  #pragma unroll
  for (int i=0;i<4;i++) acc[i]=(float4_t)(0.f);
  const int ar = tid>>2, ak = (tid&3)*8;
  const int bk = tid>>3, bn = (tid&7)*8;
  for (int kk=0; kk<H_; kk+=32){
    __syncthreads();
    *(half8_t*)&As[ar*32+ak] = *(const half8_t*)(h2 + (size_t)(row0+ar)*H_ + kk + ak);
    {
      const float* src = Wr + (size_t)(256 + kk + bk)*N5_ + n0 + bn;
      float4_t f0 = *(const float4_t*)src, f1 = *(const float4_t*)(src+4);
      float v[8]={f0.x,f0.y,f0.z,f0.w,f1.x,f1.y,f1.z,f1.w};
      #pragma unroll
      for (int j=0;j<8;j++) Bs[(bn+j)*32+bk] = (_Float16)v[j];
    }
    __syncthreads();
    half8_t a = *(const half8_t*)&As[(wave*16+ml)*32 + quad*8];
    #pragma unroll
    for (int nt=0; nt<4; nt++){
      half8_t b8 = *(const half8_t*)&Bs[(nt*16+ml)*32 + quad*8];
      acc[nt] = __builtin_amdgcn_mfma_f32_16x16x32_f16(a, b8, acc[nt], 0,0,0);
    }
  }
  #pragma unroll
  for (int nt=0; nt<4; nt++){
    #pragma unroll
    for (int r=0;r<4;r++){
      int row = row0 + wave*16 + quad*4 + r;
      int col = n0 + nt*16 + ml;
      R2[(size_t)row*N5_ + col] = (_Float16)(acc[nt][r] + br[col]);
    }
  }
}

// ---------------------------------------------------------------------------
// K3 v10: schedule-driven deep prefetch.
//  - Theorem: top-of-stack before step s == output of step s-1, so
//    tag(reduce s) = (trs[s-1]==SHIFT) ? src(s-1) : -1, and src depends only
//    on the shift count. A register cursor runs PFD=4 steps ahead issuing
//    R2 (2-deep FIFO) and h2/c2 (4-deep FIFO) prefetches into named regs.
//  - Barriers are raw "s_waitcnt lgkmcnt(0); s_barrier" — no vmcnt drain, so
//    prefetches stay in flight across barriers. Shifts take ONE barrier.
//  - Weights: 240 AGPRs resident + gate3cg3/gate4 from LDS (R9 scheme).
// LDS layout (bytes):
//   [0,81920)        wlds  u4v (gate3cg3 + gate4)
//   [81920,90112)    sh_   float[8][256]
//   [90112,98304)    sc_   float[8][256]
//   [98304,100352)   sI8   char[8][256]
//   [100352,102400)  trs   int[512]
// ---------------------------------------------------------------------------
#define K3_LDS_BYTES 102400

#define FULLG(X, g) X(g,0,0) X(g,0,1) X(g,0,2) X(g,0,3) X(g,1,0) X(g,1,1) X(g,1,2) X(g,1,3) \
                    X(g,2,0) X(g,2,1) X(g,2,2) X(g,2,3) X(g,3,0) X(g,3,1) X(g,3,2) X(g,3,3)
#define G3RES(X) X(3,0,0) X(3,0,1) X(3,0,2) X(3,0,3) X(3,1,0) X(3,1,1) X(3,1,2) X(3,1,3) \
                 X(3,2,0) X(3,2,1) X(3,2,2) X(3,2,3)
#define ALLRES(X) FULLG(X,0) FULLG(X,1) FULLG(X,2) G3RES(X)
#define OLIST(X) X(0,0) X(0,1) X(0,2) X(0,3) X(1,0) X(1,1) X(1,2) X(1,3) \
                 X(2,0) X(2,1) X(2,2) X(2,3) X(3,0) X(3,1) X(3,2) X(3,3)

#define DECLF(g,cg,kc) u4v bf##g##_##cg##_##kc;
#define LOADF(g,cg,kc) bf##g##_##cg##_##kc = wb[((g)*16 + (cg)*4 + (kc))*64];
#define OL(cg,kc) const u4v of##cg##_##kc = lwb[(4 + (cg)*4 + (kc))*64];

#define MFA(ACC, AF, BF) asm volatile("v_mfma_i32_16x16x64_i8 %0, %1, %2, %0" \
    : "+v"(ACC) : "v"(AF), "a"(BF));
#define MFV(ACC, AF, BF) asm volatile("v_mfma_i32_16x16x64_i8 %0, %1, %2, %0" \
    : "+v"(ACC) : "v"(AF), "v"(BF));
#define FENCE_IN(A0,A1,A2,A3)  asm volatile("s_nop 1" : "+v"(A0), "+v"(A1), "+v"(A2), "+v"(A3));
#define FENCE_OUT(A0,A1,A2,A3) asm volatile("s_nop 7\n\ts_nop 7" : "+v"(A0), "+v"(A1), "+v"(A2), "+v"(A3));
#define BARRIER() asm volatile("s_waitcnt lgkmcnt(0)\n\ts_barrier" ::: "memory")

#define GCHAIN_RES(g, DST) { \
  i4v A0={0,0,0,0}, A1={0,0,0,0}, A2={0,0,0,0}, A3={0,0,0,0}; \
  FENCE_IN(A0,A1,A2,A3) \
  MFA(A0,af0,bf##g##_0_0) MFA(A1,af0,bf##g##_1_0) MFA(A2,af0,bf##g##_2_0) MFA(A3,af0,bf##g##_3_0) \
  MFA(A0,af1,bf##g##_0_1) MFA(A1,af1,bf##g##_1_1) MFA(A2,af1,bf##g##_2_1) MFA(A3,af1,bf##g##_3_1) \
  MFA(A0,af2,bf##g##_0_2) MFA(A1,af2,bf##g##_1_2) MFA(A2,af2,bf##g##_2_2) MFA(A3,af2,bf##g##_3_2) \
  MFA(A0,af3,bf##g##_0_3) MFA(A1,af3,bf##g##_1_3) MFA(A2,af3,bf##g##_2_3) MFA(A3,af3,bf##g##_3_3) \
  FENCE_OUT(A0,A1,A2,A3) \
  DST = quad==0 ? A0.x : quad==1 ? A1.x : quad==2 ? A2.x : A3.x; }

__global__ __launch_bounds__(256, 1) void k3_scan(
    const int* __restrict__ trans, const _Float16* __restrict__ h2, const _Float16* __restrict__ c2,
    const _Float16* __restrict__ R2, const uint4* __restrict__ W4,
    const float* __restrict__ scales, const float* __restrict__ Wr,
    const float* __restrict__ br, float* __restrict__ out){
  extern __shared__ char smem[];
  u4v*  wlds   = (u4v*)smem;
  float* sh_   = (float*)(smem + 81920);
  float* sc_   = (float*)(smem + 90112);
  char*  sI8   = (char*)(smem + 98304);
  const u4v* sI4 = (const u4v*)(smem + 98304);
  int* trs     = (int*)(smem + 100352);

  const int b = blockIdx.x, tid = threadIdx.x;
  const int lane = tid & 63, w = tid >> 6;
  const int quad = (lane >> 4);

  const u4v* WB4v = (const u4v*)W4;
  const u4v* wb   = WB4v + (size_t)w*5120 + lane;

  // resident B-frags: gates 0..2 + gate3 cg0..2 (240 AGPRs, under 256 cap)
  ALLRES(DECLF)
  ALLRES(LOADF)

  // gate3 cg3 + gate4 -> LDS
  #pragma unroll
  for (int t=0; t<20; t++){
    const int flat = t*256 + tid;
    const int q = flat >> 6, l2 = flat & 63;
    const int ww = q / 20, j = q % 20;
    wlds[flat] = WB4v[(size_t)(ww*80 + 60 + j)*64 + l2];
  }
  const u4v* lwb = wlds + (size_t)w*1280 + lane;

  const float scf0 = scales[tid       ] * (1.f/127.f);
  const float scf1 = scales[tid +  256] * (1.f/127.f);
  const float scf2 = scales[tid +  512] * (1.f/127.f);
  const float scf3 = scales[tid +  768] * (1.f/127.f);
  const float scf4 = scales[tid + 1024] * (1.f/127.f);

  trs[tid] = (tid < NSTEPS) ? trans[(size_t)tid*B_ + b] : 1;
  { int j = 256 + tid; if (j < NSTEPS) trs[j] = trans[(size_t)j*B_ + b]; }
  #pragma unroll
  for (int d=0; d<DMAX; d++){ sh_[d*H_+tid]=0.f; sc_[d*H_+tid]=0.f; sI8[d*H_+tid]=0; }
  __syncthreads();   // trs + stack init visible before cursor prologue

  // ---- prefetch FIFOs (named regs) + schedule cursor ----
  _Float16 rA0=0,rB0=0,rC0=0,rD0=0,rE0=0, rA1=0,rB1=0,rC1=0,rD1=0,rE1=0;
  _Float16 fH0=0,fC0=0, fH1=0,fC1=0, fH2=0,fC2=0, fH3=0,fC3=0;
  int rIss=0, rCons=0, hIss=0, hCons=0;
  int cs=0, cbptr=T_, clast=-1;

  auto ADVANCE = [&](){
    if (cs < NSTEPS){
      const int ctr = trs[cs];
      if (ctr == 0){
        int csrc = cbptr - 1; if (csrc < 0) csrc = 0;
        const size_t o = ((size_t)b*T_ + csrc)*H_ + tid;
        switch (hIss & 3){
          case 0:  fH0 = h2[o]; fC0 = c2[o]; break;
          case 1:  fH1 = h2[o]; fC1 = c2[o]; break;
          case 2:  fH2 = h2[o]; fC2 = c2[o]; break;
          default: fH3 = h2[o]; fC3 = c2[o]; break;
        }
        hIss++;
        cbptr -= 1;
        clast = csrc;
      } else {
        if (clast >= 0){
          const _Float16* rr = R2 + ((size_t)b*T_ + clast)*N5_ + tid;
          if (rIss & 1){ rA1=rr[0]; rB1=rr[256]; rC1=rr[512]; rD1=rr[768]; rE1=rr[1024]; }
          else         { rA0=rr[0]; rB0=rr[256]; rC0=rr[512]; rD0=rr[768]; rE0=rr[1024]; }
          rIss++;
        }
        clast = -1;
      }
      cs++;
    }
  };
  #pragma unroll
  for (int i=0;i<PFD;i++) ADVANCE();

  int sp = 0, bptr = T_;
  int prev_src = -1;   // src if previous step was a shift, else -1

  for (int step=0; step<NSTEPS; step++){
    BARRIER();                               // prior writes visible (no vmcnt drain)
    const int tr = trs[step];
    if (tr == 0){                            // ---- SHIFT: one barrier only
      const int nbp = bptr - 1;
      const int src = nbp > 0 ? nbp : 0;
      const int slot = sp < 0 ? 0 : (sp > DMAX-1 ? DMAX-1 : sp);
      float wh, wc;
      switch (hCons & 3){                    // consume h/c FIFO head
        case 0:  wh=(float)fH0; wc=(float)fC0; break;
        case 1:  wh=(float)fH1; wc=(float)fC1; break;
        case 2:  wh=(float)fH2; wc=(float)fC2; break;
        default: wh=(float)fH3; wc=(float)fC3; break;
      }
      hCons++;
      ADVANCE();                             // issue prefetches for step+PFD
      const int wq = (int)rintf(wh * 127.f);
      sh_[slot*H_+tid] = wh;
      sc_[slot*H_+tid] = wc;
      sI8[slot*H_+tid] = (char)wq;
      sp += 1; bptr = nbp; prev_src = src;
    } else {                                 // ---- REDUCE: two barriers
      int ir = sp-1 > 0 ? sp-1 : 0;
      int il = sp-2 > 0 ? sp-2 : 0;
      ir = ir > DMAX-1 ? DMAX-1 : ir;
      il = il > DMAX-1 ? DMAX-1 : il;
      const int tg = prev_src;               // theorem: top == prev step's output
      const float cl = sc_[il*H_+tid];
      const float cr = sc_[ir*H_+tid];
      const u4v af0 = sI4[il*16 +  0 + quad];
      const u4v af1 = sI4[il*16 +  4 + quad];
      const u4v af2 = sI4[il*16 +  8 + quad];
      const u4v af3 = sI4[il*16 + 12 + quad];
      const u4v lf3_0 = lwb[0*64], lf3_1 = lwb[1*64], lf3_2 = lwb[2*64], lf3_3 = lwb[3*64];
      OLIST(OL)

      float a0,a1,a2,a3,a4;
      if (tg >= 0){                          // consume R2 FIFO head
        if (rCons & 1){ a0=(float)rA1; a1=(float)rB1; a2=(float)rC1; a3=(float)rD1; a4=(float)rE1; }
        else          { a0=(float)rA0; a1=(float)rB0; a2=(float)rC0; a3=(float)rD0; a4=(float)rE0; }
        rCons++;
      } else {
        a0=br[tid]; a1=br[tid+256]; a2=br[tid+512]; a3=br[tid+768]; a4=br[tid+1024];
      }
      ADVANCE();                             // issue prefetches for step+PFD

      int d0,d1,d2,d3,d4;
      GCHAIN_RES(0, d0)
      GCHAIN_RES(1, d1)
      GCHAIN_RES(2, d2)
      { // gate 3: cg0..2 resident, cg3 from LDS
        i4v A0={0,0,0,0}, A1={0,0,0,0}, A2={0,0,0,0}, A3={0,0,0,0};
        FENCE_IN(A0,A1,A2,A3)
        MFA(A0,af0,bf3_0_0) MFA(A1,af0,bf3_1_0) MFA(A2,af0,bf3_2_0) MFV(A3,af0,lf3_0)
        MFA(A0,af1,bf3_0_1) MFA(A1,af1,bf3_1_1) MFA(A2,af1,bf3_2_1) MFV(A3,af1,lf3_1)
        MFA(A0,af2,bf3_0_2) MFA(A1,af2,bf3_1_2) MFA(A2,af2,bf3_2_2) MFV(A3,af2,lf3_2)
        MFA(A0,af3,bf3_0_3) MFA(A1,af3,bf3_1_3) MFA(A2,af3,bf3_2_3) MFV(A3,af3,lf3_3)
        FENCE_OUT(A0,A1,A2,A3)
        d3 = quad==0 ? A0.x : quad==1 ? A1.x : quad==2 ? A2.x : A3.x;
      }
      { // gate 4: all LDS frags
        i4v A0={0,0,0,0}, A1={0,0,0,0}, A2={0,0,0,0}, A3={0,0,0,0};
        FENCE_IN(A0,A1,A2,A3)
        MFV(A0,af0,of0_0) MFV(A1,af0,of1_0) MFV(A2,af0,of2_0) MFV(A3,af0,of3_0)
        MFV(A0,af1,of0_1) MFV(A1,af1,of1_1) MFV(A2,af1,of2_1) MFV(A3,af1,of3_1)
        MFV(A0,af2,of0_2) MFV(A1,af2,of1_2) MFV(A2,af2,of2_2) MFV(A3,af2,of3_2)
        MFV(A0,af3,of0_3) MFV(A1,af3,of1_3) MFV(A2,af3,of2_3) MFV(A3,af3,of3_3)
        FENCE_OUT(A0,A1,A2,A3)
        d4 = quad==0 ? A0.x : quad==1 ? A1.x : quad==2 ? A2.x : A3.x;
      }
      a0 += scf0*(float)d0; a1 += scf1*(float)d1; a2 += scf2*(float)d2;
      a3 += scf3*(float)d3; a4 += scf4*(float)d4;

      if (tg < 0){                           // cold general fallback (never taken here)
        for (int k=0; k<H_; k++){
          const float hrk = sh_[ir*H_+k];
          const float* wr = Wr + (size_t)(256+k)*N5_ + tid;
          a0 += hrk*wr[0]; a1 += hrk*wr[256]; a2 += hrk*wr[512];
          a3 += hrk*wr[768]; a4 += hrk*wr[1024];
        }
      }
      const float cnew = sigm(a1)*cl + sigm(a2)*cr + sigm(a0)*tanhf(a3);
      const float hnew = sigm(a4)*tanhf(cnew);
      const int wq = (int)rintf(hnew * 127.f);
      BARRIER();                             // reads done -> safe to overwrite
      sh_[il*H_+tid] = hnew;
      sc_[il*H_+tid] = cnew;
      sI8[il*H_+tid] = (char)wq;
      sp -= 1; prev_src = -1;
    }
  }
  BARRIER();
  int fs = sp-1 > 0 ? sp-1 : 0;
  fs = fs > DMAX-1 ? DMAX-1 : fs;
  out[(size_t)b*H_ + tid] = sh_[fs*H_+tid];
}

// ---------------------------------------------------------------------------
// Workspace layout (bytes):
//   h2     @ 0          : 16,777,216
//   c2     @ 16777216   : 16,777,216
//   R2     @ 33554432   : 83,886,080
//   W4     @ 117440512  : 327,680   (int8 MFMA B-frags, 5 gates)
//   scales @ 117768192  : 5,120
// ---------------------------------------------------------------------------
extern "C" void kernel_launch(void* const* d_in, const int* in_sizes, int n_in,
                              void* d_out, int out_size, void* d_ws, size_t ws_size,
                              hipStream_t stream){
  const float* x    = (const float*)d_in[0];
  const int*   trn  = (const int*)  d_in[1];
  const float* Wp   = (const float*)d_in[2];
  const float* bp   = (const float*)d_in[3];
  const float* Wg   = (const float*)d_in[4];
  const float* bg   = (const float*)d_in[5];
  const float* Wr   = (const float*)d_in[6];
  const float* br   = (const float*)d_in[7];
  float* out = (float*)d_out;
  char* w = (char*)d_ws;
  _Float16* h2   = (_Float16*)(w);
  _Float16* c2   = (_Float16*)(w + (size_t)16777216);
  _Float16* R2   = (_Float16*)(w + (size_t)33554432);
  uint4*    W4   = (uint4*)   (w + (size_t)117440512);
  float*    scl  = (float*)   (w + (size_t)117768192);

  hipLaunchKernelGGL(k0a_scale, dim3(1280),    dim3(64),  0, stream, Wr, scl);
  hipLaunchKernelGGL(k0b_quant, dim3(80),      dim3(256), 0, stream, Wr, scl, W4);
  hipLaunchKernelGGL(k1_proj,   dim3(512, 4),  dim3(256), 0, stream, x, Wp, bp, Wg, bg, h2, c2);
  hipLaunchKernelGGL(k2_rproj,  dim3(512, 20), dim3(256), 0, stream, h2, Wr, br, R2);
  hipLaunchKernelGGL(k3_scan,   dim3(128),     dim3(256), K3_LDS_BYTES, stream, trn, h2, c2, R2, W4, scl, Wr, br, out);
}

// Round 11
// 662.126 us; speedup vs baseline: 1.4982x; 1.4982x over previous
//
#include <hip/hip_runtime.h>
#include <hip/hip_fp16.h>
#include <math.h>

#define B_ 128
#define T_ 256
#define E_ 300
#define H_ 256
#define N5_ 1280
#define NSTEPS 511
#define DMAX 8

typedef _Float16 half8_t __attribute__((ext_vector_type(8)));
typedef float float4_t __attribute__((ext_vector_type(4)));
typedef int i4v __attribute__((ext_vector_type(4)));
typedef unsigned int u4v __attribute__((ext_vector_type(4)));

__device__ __forceinline__ float sigm(float x){ return 1.f/(1.f + expf(-x)); }

// ---------------------------------------------------------------------------
// K0a: per-column absmax scale for hl-part of Wr (rows 0..255).
// ---------------------------------------------------------------------------
__global__ __launch_bounds__(64) void k0a_scale(const float* __restrict__ Wr,
    float* __restrict__ scales){
  const int n = blockIdx.x, t = threadIdx.x;
  float m = 0.f;
  #pragma unroll
  for (int j=0;j<4;j++) m = fmaxf(m, fabsf(Wr[(size_t)(t+64*j)*N5_ + n]));
  #pragma unroll
  for (int off=32; off; off>>=1) m = fmaxf(m, __shfl_xor(m, off, 64));
  if (t==0) scales[n] = fmaxf(m, 1e-20f) * (1.f/127.f);
}

// ---------------------------------------------------------------------------
// K0b: quantize hl-part of Wr (rows 0..255) into int8 MFMA B-fragments.
// Frag f = w*80 + g*16 + cg*4 + kc ; lane l holds col = g*256+w*64+cg*16+(l&15),
// dword r byte j -> k = kc*64 + (l>>4)*16 + r*4 + j.
// ---------------------------------------------------------------------------
__global__ __launch_bounds__(256) void k0b_quant(const float* __restrict__ Wr,
    const float* __restrict__ scales, uint4* __restrict__ W4){
  int idx = blockIdx.x*256 + threadIdx.x;
  if (idx >= 20480) return;
  const int f    = idx >> 6;
  const int lane = idx & 63;
  const int w    = f / 80;
  const int r80  = f - w*80;
  const int g    = r80 >> 4;
  const int cg   = (r80 >> 2) & 3;
  const int kc   = r80 & 3;
  const int ml   = lane & 15, quad = lane >> 4;
  const int col  = g*256 + w*64 + cg*16 + ml;
  const float inv = 1.f / scales[col];
  unsigned int d[4];
  #pragma unroll
  for (int r=0; r<4; r++){
    unsigned int acc = 0;
    #pragma unroll
    for (int j=0; j<4; j++){
      const int k = kc*64 + quad*16 + r*4 + j;
      float wv = Wr[(size_t)k*N5_ + col];
      int q = (int)rintf(wv * inv);
      q = q > 127 ? 127 : (q < -127 ? -127 : q);
      acc |= ((unsigned int)(q & 255)) << (8*j);
    }
    d[r] = acc;
  }
  uint4 v; v.x=d[0]; v.y=d[1]; v.z=d[2]; v.w=d[3];
  W4[idx] = v;
}

// ---------------------------------------------------------------------------
// K1: fused projection GEMM (unchanged).
// ---------------------------------------------------------------------------
__global__ __launch_bounds__(256) void k1_proj(
    const float* __restrict__ x, const float* __restrict__ Wp, const float* __restrict__ bp,
    const float* __restrict__ Wg, const float* __restrict__ bg,
    _Float16* __restrict__ h2, _Float16* __restrict__ c2){
  __shared__ __align__(16) _Float16 As [64*32];
  __shared__ __align__(16) _Float16 BsP[64*32];
  __shared__ __align__(16) _Float16 BsG[64*32];
  const int tid = threadIdx.x;
  const int row0 = blockIdx.x * 64;
  const int n0   = blockIdx.y * 64;
  const int wave = tid >> 6, lane = tid & 63;
  const int ml = lane & 15, quad = lane >> 4;
  float4_t accP[4], accG[4];
  #pragma unroll
  for (int i=0;i<4;i++){ accP[i]=(float4_t)(0.f); accG[i]=(float4_t)(0.f); }
  const int ar = tid >> 2, ak = (tid & 3) * 8;
  const int bk = tid >> 3, bn = (tid & 7) * 8;
  for (int kk = 0; kk < E_; kk += 32){
    __syncthreads();
    {
      const float* src = x + (size_t)(row0 + ar)*E_ + kk + ak;
      float v[8];
      #pragma unroll
      for (int q=0;q<2;q++){
        if (kk + ak + q*4 + 4 <= E_){
          float4_t f = *(const float4_t*)(src + q*4);
          v[q*4+0]=f.x; v[q*4+1]=f.y; v[q*4+2]=f.z; v[q*4+3]=f.w;
        } else {
          #pragma unroll
          for (int j=0;j<4;j++){ int kg = kk+ak+q*4+j; v[q*4+j] = (kg<E_) ? src[q*4+j] : 0.f; }
        }
      }
      #pragma unroll
      for (int j=0;j<8;j++) As[ar*32 + ak + j] = (_Float16)v[j];
    }
    {
      const int kg = kk + bk;
      if (kg < E_){
        const float* sp_ = Wp + (size_t)kg*H_ + n0 + bn;
        const float* sg_ = Wg + (size_t)kg*H_ + n0 + bn;
        float4_t p0 = *(const float4_t*)sp_, p1 = *(const float4_t*)(sp_+4);
        float4_t g0 = *(const float4_t*)sg_, g1 = *(const float4_t*)(sg_+4);
        float pv[8]={p0.x,p0.y,p0.z,p0.w,p1.x,p1.y,p1.z,p1.w};
        float gv[8]={g0.x,g0.y,g0.z,g0.w,g1.x,g1.y,g1.z,g1.w};
        #pragma unroll
        for (int j=0;j<8;j++){ BsP[(bn+j)*32+bk]=(_Float16)pv[j]; BsG[(bn+j)*32+bk]=(_Float16)gv[j]; }
      } else {
        #pragma unroll
        for (int j=0;j<8;j++){ BsP[(bn+j)*32+bk]=(_Float16)0.f; BsG[(bn+j)*32+bk]=(_Float16)0.f; }
      }
    }
    __syncthreads();
    half8_t a = *(const half8_t*)&As[(wave*16 + ml)*32 + quad*8];
    #pragma unroll
    for (int nt=0; nt<4; nt++){
      half8_t b1 = *(const half8_t*)&BsP[(nt*16 + ml)*32 + quad*8];
      accP[nt] = __builtin_amdgcn_mfma_f32_16x16x32_f16(a, b1, accP[nt], 0,0,0);
      half8_t b2 = *(const half8_t*)&BsG[(nt*16 + ml)*32 + quad*8];
      accG[nt] = __builtin_amdgcn_mfma_f32_16x16x32_f16(a, b2, accG[nt], 0,0,0);
    }
  }
  #pragma unroll
  for (int nt=0; nt<4; nt++){
    #pragma unroll
    for (int r=0;r<4;r++){
      int row = row0 + wave*16 + quad*4 + r;
      int col = n0 + nt*16 + ml;
      float c = accP[nt][r] + bp[col];
      float g = accG[nt][r] + bg[col];
      float h = sigm(g) * tanhf(c);
      size_t o = (size_t)row*H_ + col;
      c2[o] = (_Float16)c;
      h2[o] = (_Float16)h;
    }
  }
}

// ---------------------------------------------------------------------------
// K2: R = h_buf @ Wr[256:512,:] + br -> f16 R2 (unchanged)
// ---------------------------------------------------------------------------
__global__ __launch_bounds__(256) void k2_rproj(
    const _Float16* __restrict__ h2, const float* __restrict__ Wr, const float* __restrict__ br,
    _Float16* __restrict__ R2){
  __shared__ __align__(16) _Float16 As[64*32];
  __shared__ __align__(16) _Float16 Bs[64*32];
  const int tid = threadIdx.x;
  const int row0 = blockIdx.x*64, n0 = blockIdx.y*64;
  const int wave = tid>>6, lane = tid&63, ml = lane&15, quad = lane>>4;
  float4_t acc[4];
  #pragma unroll
  for (int i=0;i<4;i++) acc[i]=(float4_t)(0.f);
  const int ar = tid>>2, ak = (tid&3)*8;
  const int bk = tid>>3, bn = (tid&7)*8;
  for (int kk=0; kk<H_; kk+=32){
    __syncthreads();
    *(half8_t*)&As[ar*32+ak] = *(const half8_t*)(h2 + (size_t)(row0+ar)*H_ + kk + ak);
    {
      const float* src = Wr + (size_t)(256 + kk + bk)*N5_ + n0 + bn;
      float4_t f0 = *(const float4_t*)src, f1 = *(const float4_t*)(src+4);
      float v[8]={f0.x,f0.y,f0.z,f0.w,f1.x,f1.y,f1.z,f1.w};
      #pragma unroll
      for (int j=0;j<8;j++) Bs[(bn+j)*32+bk] = (_Float16)v[j];
    }
    __syncthreads();
    half8_t a = *(const half8_t*)&As[(wave*16+ml)*32 + quad*8];
    #pragma unroll
    for (int nt=0; nt<4; nt++){
      half8_t b8 = *(const half8_t*)&Bs[(nt*16+ml)*32 + quad*8];
      acc[nt] = __builtin_amdgcn_mfma_f32_16x16x32_f16(a, b8, acc[nt], 0,0,0);
    }
  }
  #pragma unroll
  for (int nt=0; nt<4; nt++){
    #pragma unroll
    for (int r=0;r<4;r++){
      int row = row0 + wave*16 + quad*4 + r;
      int col = n0 + nt*16 + ml;
      R2[(size_t)row*N5_ + col] = (_Float16)(acc[nt][r] + br[col]);
    }
  }
}

// ---------------------------------------------------------------------------
// K3 v11: pattern-specialized pair loop (S S (R S)* R), static double-buffer.
//  - Stack depth is constant 2: reduce reads slots{0,1}, writes slot0; shift
//    writes slot1. Prefetch slots pA*/pB* are NAMED registers (no indexing),
//    filled 2 pairs (>2000 cyc) ahead -> precise vmcnt, zero scratch.
//  - Token h never used (hr via precomputed R2; hl = prev reduce output), so
//    shifts move only a c value.
//  - Weights: 240 AGPRs resident + gate3cg3/gate4 in LDS (R9 scheme).
//  - Pattern verified per block via __syncthreads_and; generic fallback loop
//    (direct loads, R10 logic) if mismatch.
// LDS layout (bytes):
//   [0,81920)        wlds  u4v (gate3cg3 + gate4)
//   [81920,90112)    sh_   float[8][256]   (generic path only)
//   [90112,98304)    sc_   float[8][256]   (fast path uses slots 0,1)
//   [98304,100352)   sI8   char[8][256]
//   [100352,102400)  trs   int[512]
// ---------------------------------------------------------------------------
#define K3_LDS_BYTES 102400

#define FULLG(X, g) X(g,0,0) X(g,0,1) X(g,0,2) X(g,0,3) X(g,1,0) X(g,1,1) X(g,1,2) X(g,1,3) \
                    X(g,2,0) X(g,2,1) X(g,2,2) X(g,2,3) X(g,3,0) X(g,3,1) X(g,3,2) X(g,3,3)
#define G3RES(X) X(3,0,0) X(3,0,1) X(3,0,2) X(3,0,3) X(3,1,0) X(3,1,1) X(3,1,2) X(3,1,3) \
                 X(3,2,0) X(3,2,1) X(3,2,2) X(3,2,3)
#define ALLRES(X) FULLG(X,0) FULLG(X,1) FULLG(X,2) G3RES(X)
#define OLIST(X) X(0,0) X(0,1) X(0,2) X(0,3) X(1,0) X(1,1) X(1,2) X(1,3) \
                 X(2,0) X(2,1) X(2,2) X(2,3) X(3,0) X(3,1) X(3,2) X(3,3)

#define DECLF(g,cg,kc) u4v bf##g##_##cg##_##kc;
#define LOADF(g,cg,kc) bf##g##_##cg##_##kc = wb[((g)*16 + (cg)*4 + (kc))*64];
#define OL(cg,kc) const u4v of##cg##_##kc = lwb[(4 + (cg)*4 + (kc))*64];

#define MFA(ACC, AF, BF) asm volatile("v_mfma_i32_16x16x64_i8 %0, %1, %2, %0" \
    : "+v"(ACC) : "v"(AF), "a"(BF));
#define MFV(ACC, AF, BF) asm volatile("v_mfma_i32_16x16x64_i8 %0, %1, %2, %0" \
    : "+v"(ACC) : "v"(AF), "v"(BF));
#define FENCE_IN(A0,A1,A2,A3)  asm volatile("s_nop 1" : "+v"(A0), "+v"(A1), "+v"(A2), "+v"(A3));
#define FENCE_OUT(A0,A1,A2,A3) asm volatile("s_nop 7\n\ts_nop 7" : "+v"(A0), "+v"(A1), "+v"(A2), "+v"(A3));
#define BARRIER() asm volatile("s_waitcnt lgkmcnt(0)\n\ts_barrier" ::: "memory")

#define GCHAIN_RES(g, DST) { \
  i4v A0={0,0,0,0}, A1={0,0,0,0}, A2={0,0,0,0}, A3={0,0,0,0}; \
  FENCE_IN(A0,A1,A2,A3) \
  MFA(A0,af0,bf##g##_0_0) MFA(A1,af0,bf##g##_1_0) MFA(A2,af0,bf##g##_2_0) MFA(A3,af0,bf##g##_3_0) \
  MFA(A0,af1,bf##g##_0_1) MFA(A1,af1,bf##g##_1_1) MFA(A2,af1,bf##g##_2_1) MFA(A3,af1,bf##g##_3_1) \
  MFA(A0,af2,bf##g##_0_2) MFA(A1,af2,bf##g##_1_2) MFA(A2,af2,bf##g##_2_2) MFA(A3,af2,bf##g##_3_2) \
  MFA(A0,af3,bf##g##_0_3) MFA(A1,af3,bf##g##_1_3) MFA(A2,af3,bf##g##_2_3) MFA(A3,af3,bf##g##_3_3) \
  FENCE_OUT(A0,A1,A2,A3) \
  DST = quad==0 ? A0.x : quad==1 ? A1.x : quad==2 ? A2.x : A3.x; }

#define GCHAIN_G3(DST) { \
  i4v A0={0,0,0,0}, A1={0,0,0,0}, A2={0,0,0,0}, A3={0,0,0,0}; \
  FENCE_IN(A0,A1,A2,A3) \
  MFA(A0,af0,bf3_0_0) MFA(A1,af0,bf3_1_0) MFA(A2,af0,bf3_2_0) MFV(A3,af0,lf3_0) \
  MFA(A0,af1,bf3_0_1) MFA(A1,af1,bf3_1_1) MFA(A2,af1,bf3_2_1) MFV(A3,af1,lf3_1) \
  MFA(A0,af2,bf3_0_2) MFA(A1,af2,bf3_1_2) MFA(A2,af2,bf3_2_2) MFV(A3,af2,lf3_2) \
  MFA(A0,af3,bf3_0_3) MFA(A1,af3,bf3_1_3) MFA(A2,af3,bf3_2_3) MFV(A3,af3,lf3_3) \
  FENCE_OUT(A0,A1,A2,A3) \
  DST = quad==0 ? A0.x : quad==1 ? A1.x : quad==2 ? A2.x : A3.x; }

#define GCHAIN_G4(DST) { \
  i4v A0={0,0,0,0}, A1={0,0,0,0}, A2={0,0,0,0}, A3={0,0,0,0}; \
  FENCE_IN(A0,A1,A2,A3) \
  MFV(A0,af0,of0_0) MFV(A1,af0,of1_0) MFV(A2,af0,of2_0) MFV(A3,af0,of3_0) \
  MFV(A0,af1,of0_1) MFV(A1,af1,of1_1) MFV(A2,af1,of2_1) MFV(A3,af1,of3_1) \
  MFV(A0,af2,of0_2) MFV(A1,af2,of1_2) MFV(A2,af2,of2_2) MFV(A3,af2,of3_2) \
  MFV(A0,af3,of0_3) MFV(A1,af3,of1_3) MFV(A2,af3,of2_3) MFV(A3,af3,of3_3) \
  FENCE_OUT(A0,A1,A2,A3) \
  DST = quad==0 ? A0.x : quad==1 ? A1.x : quad==2 ? A2.x : A3.x; }

// One (reduce, shift) pair in the pattern path. PX is pA or pB (named slot).
// Consumes R2 row (254-i) + token c (253-i); issues prefetch for pair i+2.
#define PAIR_STEP(IDX, PX) { \
  BARRIER(); \
  float a0=(float)PX##0, a1=(float)PX##1, a2=(float)PX##2, a3=(float)PX##3, a4=(float)PX##4; \
  const float tc = (float)PX##c; \
  const float cl = sc_[tid]; \
  const float cr = sc_[H_+tid]; \
  const u4v af0 = sI4[quad], af1 = sI4[4+quad], af2 = sI4[8+quad], af3 = sI4[12+quad]; \
  const u4v lf3_0 = lwb[0*64], lf3_1 = lwb[1*64], lf3_2 = lwb[2*64], lf3_3 = lwb[3*64]; \
  OLIST(OL) \
  { int rrow = 252-(IDX); if (rrow < 0) rrow = 0; \
    const _Float16* rr = R2 + ((size_t)b*T_ + rrow)*N5_ + tid; \
    PX##0=rr[0]; PX##1=rr[256]; PX##2=rr[512]; PX##3=rr[768]; PX##4=rr[1024]; \
    int crow = 251-(IDX); if (crow < 0) crow = 0; \
    PX##c = c2[((size_t)b*T_ + crow)*H_ + tid]; } \
  int d0,d1,d2,d3,d4; \
  GCHAIN_RES(0, d0) \
  GCHAIN_RES(1, d1) \
  GCHAIN_RES(2, d2) \
  GCHAIN_G3(d3) \
  GCHAIN_G4(d4) \
  a0 += scf0*(float)d0; a1 += scf1*(float)d1; a2 += scf2*(float)d2; \
  a3 += scf3*(float)d3; a4 += scf4*(float)d4; \
  const float cnew = sigm(a1)*cl + sigm(a2)*cr + sigm(a0)*tanhf(a3); \
  const float hnew = sigm(a4)*tanhf(cnew); \
  const int wq = (int)rintf(hnew*127.f); \
  BARRIER(); \
  sc_[tid]     = cnew; \
  sI8[tid]     = (char)wq; \
  sc_[H_+tid]  = tc; \
}

__global__ __launch_bounds__(256, 1) void k3_scan(
    const int* __restrict__ trans, const _Float16* __restrict__ h2, const _Float16* __restrict__ c2,
    const _Float16* __restrict__ R2, const uint4* __restrict__ W4,
    const float* __restrict__ scales, const float* __restrict__ Wr,
    const float* __restrict__ br, float* __restrict__ out){
  extern __shared__ char smem[];
  u4v*  wlds   = (u4v*)smem;
  float* sh_   = (float*)(smem + 81920);
  float* sc_   = (float*)(smem + 90112);
  char*  sI8   = (char*)(smem + 98304);
  const u4v* sI4 = (const u4v*)(smem + 98304);
  int* trs     = (int*)(smem + 100352);

  const int b = blockIdx.x, tid = threadIdx.x;
  const int lane = tid & 63, w = tid >> 6;
  const int quad = (lane >> 4);

  const u4v* WB4v = (const u4v*)W4;
  const u4v* wb   = WB4v + (size_t)w*5120 + lane;

  // resident B-frags: gates 0..2 + gate3 cg0..2 (240 AGPRs, under 256 cap)
  ALLRES(DECLF)
  ALLRES(LOADF)

  // gate3 cg3 + gate4 -> LDS
  #pragma unroll
  for (int t=0; t<20; t++){
    const int flat = t*256 + tid;
    const int q = flat >> 6, l2 = flat & 63;
    const int ww = q / 20, j = q % 20;
    wlds[flat] = WB4v[(size_t)(ww*80 + 60 + j)*64 + l2];
  }
  const u4v* lwb = wlds + (size_t)w*1280 + lane;

  const float scf0 = scales[tid       ] * (1.f/127.f);
  const float scf1 = scales[tid +  256] * (1.f/127.f);
  const float scf2 = scales[tid +  512] * (1.f/127.f);
  const float scf3 = scales[tid +  768] * (1.f/127.f);
  const float scf4 = scales[tid + 1024] * (1.f/127.f);

  trs[tid] = (tid < NSTEPS) ? trans[(size_t)tid*B_ + b] : 1;
  { int j = 256 + tid; if (j < NSTEPS) trs[j] = trans[(size_t)j*B_ + b]; }
  #pragma unroll
  for (int d=0; d<DMAX; d++){ sh_[d*H_+tid]=0.f; sc_[d*H_+tid]=0.f; sI8[d*H_+tid]=0; }

  // pattern check: S S (R S)* with even steps >=2 reduce, odd steps shift
  int myok = 1;
  { int s = tid;
    if (s < NSTEPS){ int e = (s>=2 && (s&1)==0) ? 1 : 0; if (trs[s]!=e) myok=0; } }
  { int s = tid + 256;
    if (s < NSTEPS){ int e = ((s&1)==0) ? 1 : 0; if (trs[s]!=e) myok=0; } }
  const int ok = __syncthreads_and(myok);   // also orders trs/stack init

  if (ok){
    // ---------------- fast pattern path ----------------
    const size_t hb = (size_t)b*T_*H_;
    // prologue tokens: slot0 = token 255 (c + int8 h), slot1 = token 254 (c)
    const _Float16 h255 = h2[hb + 255*H_ + tid];
    const _Float16 c255 = c2[hb + 255*H_ + tid];
    const _Float16 c254 = c2[hb + 254*H_ + tid];
    // prefetch pair0 -> slotA (R2 row 254, token c 253)
    _Float16 pA0,pA1,pA2,pA3,pA4,pAc;
    { const _Float16* rr = R2 + ((size_t)b*T_ + 254)*N5_ + tid;
      pA0=rr[0]; pA1=rr[256]; pA2=rr[512]; pA3=rr[768]; pA4=rr[1024];
      pAc = c2[hb + 253*H_ + tid]; }
    // prefetch pair1 -> slotB (R2 row 253, token c 252)
    _Float16 pB0,pB1,pB2,pB3,pB4,pBc;
    { const _Float16* rr = R2 + ((size_t)b*T_ + 253)*N5_ + tid;
      pB0=rr[0]; pB1=rr[256]; pB2=rr[512]; pB3=rr[768]; pB4=rr[1024];
      pBc = c2[hb + 252*H_ + tid]; }
    sc_[tid]    = (float)c255;
    sI8[tid]    = (char)(int)rintf((float)h255 * 127.f);
    sc_[H_+tid] = (float)c254;
    // 254 full pairs, unrolled x2 for static slots
    #pragma unroll 1
    for (int i=0; i<254; i+=2){
      PAIR_STEP(i,   pA)
      PAIR_STEP(i+1, pB)
    }
    // final reduce (pair 254, slotA: R2 row 0, cr = token 0)
    {
      BARRIER();
      float a0=(float)pA0, a1=(float)pA1, a2=(float)pA2, a3=(float)pA3, a4=(float)pA4;
      const float cl = sc_[tid];
      const float cr = sc_[H_+tid];
      const u4v af0 = sI4[quad], af1 = sI4[4+quad], af2 = sI4[8+quad], af3 = sI4[12+quad];
      const u4v lf3_0 = lwb[0*64], lf3_1 = lwb[1*64], lf3_2 = lwb[2*64], lf3_3 = lwb[3*64];
      OLIST(OL)
      int d0,d1,d2,d3,d4;
      GCHAIN_RES(0, d0)
      GCHAIN_RES(1, d1)
      GCHAIN_RES(2, d2)
      GCHAIN_G3(d3)
      GCHAIN_G4(d4)
      a0 += scf0*(float)d0; a1 += scf1*(float)d1; a2 += scf2*(float)d2;
      a3 += scf3*(float)d3; a4 += scf4*(float)d4;
      const float cnew = sigm(a1)*cl + sigm(a2)*cr + sigm(a0)*tanhf(a3);
      const float hnew = sigm(a4)*tanhf(cnew);
      out[(size_t)b*H_ + tid] = hnew;
    }
    return;
  }

  // ---------------- generic fallback (direct loads, R10 logic) ----------------
  int sp = 0, bptr = T_, prev_src = -1;
  for (int step=0; step<NSTEPS; step++){
    __syncthreads();
    const int tr = trs[step];
    if (tr == 0){                            // SHIFT (trans uniform per block)
      const int nbp = bptr - 1;
      const int src = nbp > 0 ? nbp : 0;
      const int slot = sp < 0 ? 0 : (sp > DMAX-1 ? DMAX-1 : sp);
      const size_t o = ((size_t)b*T_ + src)*H_ + tid;
      const float wh = (float)h2[o], wc = (float)c2[o];
      sh_[slot*H_+tid] = wh;
      sc_[slot*H_+tid] = wc;
      sI8[slot*H_+tid] = (char)(int)rintf(wh * 127.f);
      sp += 1; bptr = nbp; prev_src = src;
    } else {                                 // REDUCE
      int ir = sp-1 > 0 ? sp-1 : 0;
      int il = sp-2 > 0 ? sp-2 : 0;
      ir = ir > DMAX-1 ? DMAX-1 : ir;
      il = il > DMAX-1 ? DMAX-1 : il;
      const int tg = prev_src;
      const float cl = sc_[il*H_+tid];
      const float cr = sc_[ir*H_+tid];
      const u4v af0 = sI4[il*16 +  0 + quad];
      const u4v af1 = sI4[il*16 +  4 + quad];
      const u4v af2 = sI4[il*16 +  8 + quad];
      const u4v af3 = sI4[il*16 + 12 + quad];
      const u4v lf3_0 = lwb[0*64], lf3_1 = lwb[1*64], lf3_2 = lwb[2*64], lf3_3 = lwb[3*64];
      OLIST(OL)
      float a0,a1,a2,a3,a4;
      if (tg >= 0){
        const _Float16* rr = R2 + ((size_t)b*T_ + tg)*N5_ + tid;
        a0=(float)rr[0]; a1=(float)rr[256]; a2=(float)rr[512]; a3=(float)rr[768]; a4=(float)rr[1024];
      } else {
        a0=br[tid]; a1=br[tid+256]; a2=br[tid+512]; a3=br[tid+768]; a4=br[tid+1024];
      }
      int d0,d1,d2,d3,d4;
      GCHAIN_RES(0, d0)
      GCHAIN_RES(1, d1)
      GCHAIN_RES(2, d2)
      GCHAIN_G3(d3)
      GCHAIN_G4(d4)
      a0 += scf0*(float)d0; a1 += scf1*(float)d1; a2 += scf2*(float)d2;
      a3 += scf3*(float)d3; a4 += scf4*(float)d4;
      if (tg < 0){                           // general hr fallback
        for (int k=0; k<H_; k++){
          const float hrk = sh_[ir*H_+k];
          const float* wr = Wr + (size_t)(256+k)*N5_ + tid;
          a0 += hrk*wr[0]; a1 += hrk*wr[256]; a2 += hrk*wr[512];
          a3 += hrk*wr[768]; a4 += hrk*wr[1024];
        }
      }
      const float cnew = sigm(a1)*cl + sigm(a2)*cr + sigm(a0)*tanhf(a3);
      const float hnew = sigm(a4)*tanhf(cnew);
      const int wq = (int)rintf(hnew * 127.f);
      __syncthreads();
      sh_[il*H_+tid] = hnew;
      sc_[il*H_+tid] = cnew;
      sI8[il*H_+tid] = (char)wq;
      sp -= 1; prev_src = -1;
    }
  }
  __syncthreads();
  int fs = sp-1 > 0 ? sp-1 : 0;
  fs = fs > DMAX-1 ? DMAX-1 : fs;
  out[(size_t)b*H_ + tid] = sh_[fs*H_+tid];
}

// ---------------------------------------------------------------------------
// Workspace layout (bytes):
//   h2     @ 0          : 16,777,216
//   c2     @ 16777216   : 16,777,216
//   R2     @ 33554432   : 83,886,080
//   W4     @ 117440512  : 327,680   (int8 MFMA B-frags, 5 gates)
//   scales @ 117768192  : 5,120
// ---------------------------------------------------------------------------
extern "C" void kernel_launch(void* const* d_in, const int* in_sizes, int n_in,
                              void* d_out, int out_size, void* d_ws, size_t ws_size,
                              hipStream_t stream){
  const float* x    = (const float*)d_in[0];
  const int*   trn  = (const int*)  d_in[1];
  const float* Wp   = (const float*)d_in[2];
  const float* bp   = (const float*)d_in[3];
  const float* Wg   = (const float*)d_in[4];
  const float* bg   = (const float*)d_in[5];
  const float* Wr   = (const float*)d_in[6];
  const float* br   = (const float*)d_in[7];
  float* out = (float*)d_out;
  char* w = (char*)d_ws;
  _Float16* h2   = (_Float16*)(w);
  _Float16* c2   = (_Float16*)(w + (size_t)16777216);
  _Float16* R2   = (_Float16*)(w + (size_t)33554432);
  uint4*    W4   = (uint4*)   (w + (size_t)117440512);
  float*    scl  = (float*)   (w + (size_t)117768192);

  hipLaunchKernelGGL(k0a_scale, dim3(1280),    dim3(64),  0, stream, Wr, scl);
  hipLaunchKernelGGL(k0b_quant, dim3(80),      dim3(256), 0, stream, Wr, scl, W4);
  hipLaunchKernelGGL(k1_proj,   dim3(512, 4),  dim3(256), 0, stream, x, Wp, bp, Wg, bg, h2, c2);
  hipLaunchKernelGGL(k2_rproj,  dim3(512, 20), dim3(256), 0, stream, h2, Wr, br, R2);
  hipLaunchKernelGGL(k3_scan,   dim3(128),     dim3(256), K3_LDS_BYTES, stream, trn, h2, c2, R2, W4, scl, Wr, br, out);
}